// Round 7
// baseline (161.136 us; speedup 1.0000x reference)
//
#include <hip/hip_runtime.h>
#include <hip/hip_bf16.h>
#include <math.h>

#define HH 64
#define WW 64
#define CH 256
#define NB 2
#define HWSZ (HH*WW)        // 4096
#define PIX (NB*HWSZ)       // 8192

typedef __attribute__((ext_vector_type(8))) short bf16x8;
typedef __attribute__((ext_vector_type(4))) float f32x4;

static __device__ __forceinline__ ushort f2bf(float f){
  union { __hip_bfloat16 h; ushort u; } cv;
  cv.h = __float2bfloat16(f);   // round-to-nearest-even
  return cv.u;
}
static __device__ __forceinline__ float bflo(uint u){ return __uint_as_float(u << 16); }
static __device__ __forceinline__ float bfhi(uint u){ return __uint_as_float(u & 0xffff0000u); }

// ---------------- prep: b<2048 NCHW->NHWC transpose; 2048..2495 weight prep; 2496 bias ----------------
__global__ __launch_bounds__(256) void k_prep(const float* __restrict__ x,
    float* __restrict__ out32, ushort* __restrict__ out16,
    const float* __restrict__ a_in_w, const float* __restrict__ a_off_w,
    const float* __restrict__ a_mk_w, const float* __restrict__ a_out_w,
    const float* __restrict__ b_in_w, const float* __restrict__ b_off_w,
    const float* __restrict__ b_mk_w, const float* __restrict__ b_out_w,
    const float* __restrict__ proj_w, ushort* __restrict__ Bt,
    const float* __restrict__ a_off_b, const float* __restrict__ a_mk_b,
    const float* __restrict__ b_off_b, const float* __restrict__ b_mk_b,
    float* __restrict__ bcatA, float* __restrict__ bcatB){
  __shared__ float t[32][33];
  int b = blockIdx.x;
  int tid = threadIdx.x;
  int tx = tid & 31, ty = tid >> 5;           // 32 x 8
  if (b < 2048) {
    int n = b >> 10, rem = b & 1023;
    int p0 = (rem & 127) * 32, c0 = (rem >> 7) * 32;
    const float* inn = x + (size_t)n * CH * HWSZ;
    float* o32 = out32 + (size_t)n * HWSZ * CH;
    ushort* o16 = out16 + (size_t)n * HWSZ * CH;
    #pragma unroll
    for (int i = 0; i < 4; ++i) {
      int c = c0 + ty + i*8;
      t[ty + i*8][tx] = inn[(size_t)c * HWSZ + p0 + tx];
    }
    __syncthreads();
    #pragma unroll
    for (int i = 0; i < 4; ++i) {
      int p = p0 + ty + i*8;
      float val = t[tx][ty + i*8];
      o32[(size_t)p * CH + c0 + tx] = val;
      o16[(size_t)p * CH + c0 + tx] = f2bf(val);
    }
  } else if (b < 2496) {
    int zz = b - 2048;
    int z = zz >> 6, rem = zz & 63;
    int n0 = (rem & 7) * 32, k0 = (rem >> 3) * 32;
    const float* W = a_in_w; int mode = 0;
    switch(z){
      case 0: W = a_in_w; break;
      case 1: mode = 1; break;
      case 2: W = a_out_w; break;
      case 3: W = b_in_w; break;
      case 4: mode = 2; break;
      case 5: W = b_out_w; break;
      default: W = proj_w; break;
    }
    #pragma unroll
    for (int i = 0; i < 4; ++i) {
      int k = k0 + ty + i*8, nn = n0 + tx;
      float val;
      if (mode == 0) val = W[k*256 + nn];
      else {
        const float* ow = (mode == 1) ? a_off_w : b_off_w;
        const float* mw = (mode == 1) ? a_mk_w  : b_mk_w;
        val = (nn < 144) ? ow[k*144 + nn] : ((nn < 216) ? mw[k*72 + nn - 144] : 0.f);
      }
      t[ty + i*8][tx] = val;
    }
    __syncthreads();
    #pragma unroll
    for (int i = 0; i < 4; ++i) {
      int nn = n0 + ty + i*8, k = k0 + tx;
      Bt[(size_t)z*65536 + nn*256 + k] = f2bf(t[tx][ty + i*8]);
    }
  } else {
    bcatA[tid] = (tid < 144) ? a_off_b[tid] : ((tid < 216) ? a_mk_b[tid-144] : 0.f);
    bcatB[tid] = (tid < 144) ? b_off_b[tid] : ((tid < 216) ? b_mk_b[tid-144] : 0.f);
  }
}

// ================= shared GEMM core =================
// As: 64 rows x 256 K bf16, swizzled: 8-elem chunk ck stored at ck^(row&31).
// B^T global [n][k]; this block computes cols [by*64, by*64+64).
// 4 K-phases, Bs chunk 8KB staged with register prefetch. 4 waves x 16-col strips,
// each wave 4 row-tiles of 16 (register blocking 4x1: 4 af-reads + 1 bf-read -> 4 MFMAs).
// MODE: 0 = bf16 out; 1 = f32 + bf16 out; 2 = f32 out; 3 = fused gate (NCHW f32 out)
template<int MODE>
static __device__ __forceinline__ void gemm_core(ushort* As, ushort* Bs,
    int rows, int by, const ushort* __restrict__ Bt, const float* __restrict__ bias,
    float* __restrict__ Cf, ushort* __restrict__ Cb,
    const float* __restrict__ xg, float* __restrict__ outg){
  int tid = threadIdx.x;
  int w = tid >> 6, l = tid & 63;
  int lr = l & 15, lk = l >> 4;          // lk 0..3
  int br = tid >> 2, bc2 = (tid & 3) << 1;     // B staging: row 0..63, 2 chunks each
  const ushort* Bg = Bt + (size_t)(by*64 + br) * 256 + ((tid & 3) << 4);
  uint4 pb0 = *reinterpret_cast<const uint4*>(Bg);
  uint4 pb1 = *reinterpret_cast<const uint4*>(Bg + 8);
  f32x4 acc[4] = {};
  #pragma unroll
  for (int ph = 0; ph < 4; ++ph) {
    __syncthreads();
    *reinterpret_cast<uint4*>(&Bs[(br << 6) + (((bc2    ) ^ (br & 7)) << 3)]) = pb0;
    *reinterpret_cast<uint4*>(&Bs[(br << 6) + (((bc2 + 1) ^ (br & 7)) << 3)]) = pb1;
    __syncthreads();
    if (ph < 3) {
      pb0 = *reinterpret_cast<const uint4*>(Bg + (ph+1)*64);
      pb1 = *reinterpret_cast<const uint4*>(Bg + (ph+1)*64 + 8);
    }
    #pragma unroll
    for (int ks = 0; ks < 2; ++ks) {
      int col = w*16 + lr;
      bf16x8 bf = *reinterpret_cast<const bf16x8*>(&Bs[(col << 6) + ((((ks<<2) + lk) ^ (col & 7)) << 3)]);
      #pragma unroll
      for (int mi = 0; mi < 4; ++mi) {
        int row = mi*16 + lr;
        int ck = ((ph<<3) + (ks<<2) + lk) ^ (row & 31);
        bf16x8 af = *reinterpret_cast<const bf16x8*>(&As[(row << 8) + (ck << 3)]);
        acc[mi] = __builtin_amdgcn_mfma_f32_16x16x32_bf16(af, bf, acc[mi], 0, 0, 0);
      }
    }
  }
  int colg = by*64 + w*16 + lr;
  float bval = bias[colg];
  #pragma unroll
  for (int mi = 0; mi < 4; ++mi) {
    int row0 = rows + mi*16 + (lk << 2);
    if (MODE == 3) {
      int n = row0 >> 12, hw = row0 & 4095;
      size_t base = (size_t)n * (CH*HWSZ) + (size_t)colg * HWSZ + hw;
      float4 xv = *reinterpret_cast<const float4*>(&xg[base]);
      float4 ov;
      ov.x = xv.x * (acc[mi][0] + bval);
      ov.y = xv.y * (acc[mi][1] + bval);
      ov.z = xv.z * (acc[mi][2] + bval);
      ov.w = xv.w * (acc[mi][3] + bval);
      *reinterpret_cast<float4*>(&outg[base]) = ov;
    } else {
      #pragma unroll
      for (int j = 0; j < 4; ++j) {
        float val = acc[mi][j] + bval;
        if (MODE != 0) Cf[(size_t)(row0 + j) * 256 + colg] = val;
        if (MODE != 2) Cb[(size_t)(row0 + j) * 256 + colg] = f2bf(val);
      }
    }
  }
}

// stage A-tile (64x256 bf16) from global into swizzled As
static __device__ __forceinline__ void stage_A(ushort* As, const ushort* __restrict__ A, int rows){
  int tid = threadIdx.x;
  int r = tid >> 2, q0 = (tid & 3) << 3;   // 8 chunks per thread
  const ushort* Ag = A + (size_t)(rows + r) * 256 + (q0 << 3);
  #pragma unroll
  for (int i = 0; i < 8; ++i) {
    uint4 v = *reinterpret_cast<const uint4*>(Ag + (i << 3));
    *reinterpret_cast<uint4*>(&As[(r << 8) + (((q0 + i) ^ (r & 31)) << 3)]) = v;
  }
}

// ================= plain GEMM kernel (A from global bf16) =================
template<int MODE>
__global__ __launch_bounds__(256, 4) void k_gemm256(const ushort* __restrict__ A,
    const ushort* __restrict__ Bt, const float* __restrict__ bias,
    float* __restrict__ Cf, ushort* __restrict__ Cb,
    const float* __restrict__ xg, float* __restrict__ outg){
  __shared__ ushort As[64*256];
  __shared__ ushort Bs[64*64];
  int rows = blockIdx.x * 64, by = blockIdx.y;
  stage_A(As, A, rows);
  gemm_core<MODE>(As, Bs, rows, by, Bt, bias, Cf, Cb, xg, outg);
}

// ================= fused dwln + v/fm GEMM dispatch =================
// z=0: v-GEMM (A = ain bf16 global). z=1: dwln computes A-tile (f) in LDS, then fm-GEMM.
__global__ __launch_bounds__(256, 2) void k_dwg(
    const float* __restrict__ xin,    // NHWC f32 (dwconv input)
    const ushort* __restrict__ ain,   // NHWC bf16 (v-GEMM A)
    const float* __restrict__ dw_w, const float* __restrict__ dw_b,
    const float* __restrict__ ln_g, const float* __restrict__ ln_b,
    const ushort* __restrict__ Btv, const float* __restrict__ biasv,
    const ushort* __restrict__ Btf, const float* __restrict__ biasf,
    ushort* __restrict__ v16, float* __restrict__ fm32){
  __shared__ ushort As[64*256];
  __shared__ ushort Bs[64*64];
  int rows = blockIdx.x * 64, by = blockIdx.y;
  if (blockIdx.z == 0) {
    stage_A(As, ain, rows);
    gemm_core<0>(As, Bs, rows, by, Btv, biasv, nullptr, v16, nullptr, nullptr);
  } else {
    // dwconv3x3 + LN + GELU for 64 rows -> As (barrier-free: each wave owns its rows)
    int wv = threadIdx.x >> 6, l = threadIdx.x & 63;
    int c = l << 2;
    #pragma unroll 2
    for (int it = 0; it < 16; ++it) {
      int lrow = it*4 + wv;
      int pix = rows + lrow;
      int n  = pix >> 12;
      int hw = pix & 4095;
      int h = hw >> 6, w = hw & 63;
      const float* xb = xin + (size_t)n * HWSZ * CH;
      float4 bv = *reinterpret_cast<const float4*>(&dw_b[c]);
      float s0 = bv.x, s1 = bv.y, s2 = bv.z, s3 = bv.w;
      #pragma unroll
      for (int i = 0; i < 3; ++i) {
        int y = h + i - 1;
        if ((unsigned)y < 64u) {
          #pragma unroll
          for (int j = 0; j < 3; ++j) {
            int xx = w + j - 1;
            if ((unsigned)xx < 64u) {
              float4 xv = *reinterpret_cast<const float4*>(&xb[((size_t)((y<<6)+xx))*CH + c]);
              float4 wv4 = *reinterpret_cast<const float4*>(&dw_w[(i*3+j)*CH + c]);
              s0 = fmaf(xv.x, wv4.x, s0);
              s1 = fmaf(xv.y, wv4.y, s1);
              s2 = fmaf(xv.z, wv4.z, s2);
              s3 = fmaf(xv.w, wv4.w, s3);
            }
          }
        }
      }
      float v1 = s0 + s1 + s2 + s3;
      float v2 = s0*s0 + s1*s1 + s2*s2 + s3*s3;
      #pragma unroll
      for (int off = 32; off >= 1; off >>= 1) {
        v1 += __shfl_xor(v1, off);
        v2 += __shfl_xor(v2, off);
      }
      float mean = v1 * (1.f/256.f);
      float var  = v2 * (1.f/256.f) - mean*mean;
      float inv  = rsqrtf(var + 1e-5f);
      float4 gv = *reinterpret_cast<const float4*>(&ln_g[c]);
      float4 bb = *reinterpret_cast<const float4*>(&ln_b[c]);
      float z0 = (s0 - mean) * inv * gv.x + bb.x;
      float z1 = (s1 - mean) * inv * gv.y + bb.y;
      float z2 = (s2 - mean) * inv * gv.z + bb.z;
      float z3 = (s3 - mean) * inv * gv.w + bb.w;
      float g0 = 0.5f * z0 * (1.f + erff(z0 * 0.70710678118654752f));
      float g1 = 0.5f * z1 * (1.f + erff(z1 * 0.70710678118654752f));
      float g2 = 0.5f * z2 * (1.f + erff(z2 * 0.70710678118654752f));
      float g3 = 0.5f * z3 * (1.f + erff(z3 * 0.70710678118654752f));
      uint2 pk;
      pk.x = (uint)f2bf(g0) | ((uint)f2bf(g1) << 16);
      pk.y = (uint)f2bf(g2) | ((uint)f2bf(g3) << 16);
      int chunk = (l >> 1) ^ (lrow & 31);
      *reinterpret_cast<uint2*>(&As[(lrow << 8) + (chunk << 3) + ((l & 1) << 2)]) = pk;
    }
    gemm_core<2>(As, Bs, rows, by, Btf, biasf, fm32, nullptr, nullptr, nullptr);
  }
}

// ---------------- deformable sampling (wave-per-pixel, 4 ch/thread, uint2 gathers) ----------------
__global__ __launch_bounds__(256, 4) void k_sample(const ushort* __restrict__ v,
    const float* __restrict__ fm, ushort* __restrict__ o){
  __shared__ float sfm[4][256];
  int wv = threadIdx.x >> 6, l = threadIdx.x & 63;
  int pix = blockIdx.x * 4 + wv;
  int c = l << 2;
  int g = l >> 3;
  *reinterpret_cast<float4*>(&sfm[wv][c]) = *reinterpret_cast<const float4*>(&fm[(size_t)pix*256 + c]);
  __syncthreads();
  const float* fp = sfm[wv];
  float ml[9];
  float mx = -1e30f;
  #pragma unroll
  for (int k = 0; k < 9; ++k) { ml[k] = fp[144 + g*9 + k]; mx = fmaxf(mx, ml[k]); }
  float ssum = 0.f;
  #pragma unroll
  for (int k = 0; k < 9; ++k) { ml[k] = __expf(ml[k] - mx); ssum += ml[k]; }
  int n = pix >> 12;
  int hw = pix & 4095;
  int h = hw >> 6, w = hw & 63;
  const ushort* vb = v + (size_t)n * HWSZ * CH + c;
  float a0 = 0.f, a1 = 0.f, a2 = 0.f, a3 = 0.f;
  #pragma unroll
  for (int k = 0; k < 9; ++k) {
    int dx = k/3 - 1, dy = k%3 - 1;     // dx-major per meshgrid(indexing='ij')
    float ox = fp[g*18 + k*2];
    float oy = fp[g*18 + k*2 + 1];
    float xu = (float)(w + dx) + ox;
    float yu = (float)(h + dy) + oy;
    float xf = floorf(xu), yf = floorf(yu);
    float tx = xu - xf, ty = yu - yf;
    int x0 = (int)xf, y0 = (int)yf;
    int x1 = x0 + 1, y1 = y0 + 1;
    float m00 = (float)((unsigned)x0 < 64u && (unsigned)y0 < 64u);
    float m10 = (float)((unsigned)x1 < 64u && (unsigned)y0 < 64u);
    float m01 = (float)((unsigned)x0 < 64u && (unsigned)y1 < 64u);
    float m11 = (float)((unsigned)x1 < 64u && (unsigned)y1 < 64u);
    int xc0 = min(max(x0, 0), 63), xc1 = min(max(x1, 0), 63);
    int yc0 = min(max(y0, 0), 63), yc1 = min(max(y1, 0), 63);
    float w0x = 1.f - tx, w0y = 1.f - ty;
    uint2 q00 = *reinterpret_cast<const uint2*>(vb + (((yc0 << 6) + xc0) << 8));
    uint2 q10 = *reinterpret_cast<const uint2*>(vb + (((yc0 << 6) + xc1) << 8));
    uint2 q01 = *reinterpret_cast<const uint2*>(vb + (((yc1 << 6) + xc0) << 8));
    uint2 q11 = *reinterpret_cast<const uint2*>(vb + (((yc1 << 6) + xc1) << 8));
    float w00 = ml[k] * (w0x * w0y * m00);
    float w10 = ml[k] * (tx  * w0y * m10);
    float w01 = ml[k] * (w0x * ty  * m01);
    float w11 = ml[k] * (tx  * ty  * m11);
    a0 = fmaf(bflo(q00.x), w00, a0); a1 = fmaf(bfhi(q00.x), w00, a1);
    a2 = fmaf(bflo(q00.y), w00, a2); a3 = fmaf(bfhi(q00.y), w00, a3);
    a0 = fmaf(bflo(q10.x), w10, a0); a1 = fmaf(bfhi(q10.x), w10, a1);
    a2 = fmaf(bflo(q10.y), w10, a2); a3 = fmaf(bfhi(q10.y), w10, a3);
    a0 = fmaf(bflo(q01.x), w01, a0); a1 = fmaf(bfhi(q01.x), w01, a1);
    a2 = fmaf(bflo(q01.y), w01, a2); a3 = fmaf(bfhi(q01.y), w01, a3);
    a0 = fmaf(bflo(q11.x), w11, a0); a1 = fmaf(bfhi(q11.x), w11, a1);
    a2 = fmaf(bflo(q11.y), w11, a2); a3 = fmaf(bfhi(q11.y), w11, a3);
  }
  float inv = 1.f / ssum;
  uint2 pk;
  pk.x = (uint)f2bf(a0 * inv) | ((uint)f2bf(a1 * inv) << 16);
  pk.y = (uint)f2bf(a2 * inv) | ((uint)f2bf(a3 * inv) << 16);
  *reinterpret_cast<uint2*>(&o[(size_t)pix*256 + c]) = pk;
}

extern "C" void kernel_launch(void* const* d_in, const int* in_sizes, int n_in,
                              void* d_out, int out_size, void* d_ws, size_t ws_size,
                              hipStream_t stream) {
  const float* x      = (const float*)d_in[0];
  const float* a_dw_w = (const float*)d_in[1];
  const float* a_dw_b = (const float*)d_in[2];
  const float* a_ln_g = (const float*)d_in[3];
  const float* a_ln_b = (const float*)d_in[4];
  const float* a_in_w = (const float*)d_in[5];
  const float* a_in_b = (const float*)d_in[6];
  const float* a_off_w= (const float*)d_in[7];
  const float* a_off_b= (const float*)d_in[8];
  const float* a_mk_w = (const float*)d_in[9];
  const float* a_mk_b = (const float*)d_in[10];
  const float* a_out_w= (const float*)d_in[11];
  const float* a_out_b= (const float*)d_in[12];
  const float* b_dw_w = (const float*)d_in[13];
  const float* b_dw_b = (const float*)d_in[14];
  const float* b_ln_g = (const float*)d_in[15];
  const float* b_ln_b = (const float*)d_in[16];
  const float* b_in_w = (const float*)d_in[17];
  const float* b_in_b = (const float*)d_in[18];
  const float* b_off_w= (const float*)d_in[19];
  const float* b_off_b= (const float*)d_in[20];
  const float* b_mk_w = (const float*)d_in[21];
  const float* b_mk_b = (const float*)d_in[22];
  const float* b_out_w= (const float*)d_in[23];
  const float* b_out_b= (const float*)d_in[24];
  const float* proj_w = (const float*)d_in[25];
  const float* proj_b = (const float*)d_in[26];
  float* out = (float*)d_out;

  const size_t BUF = (size_t)PIX * CH;   // 2,097,152 elements
  float* bx32   = (float*)d_ws;          // x NHWC fp32
  float* fm32   = bx32 + BUF;            // offsets+mask logits fp32
  float* at1_32 = fm32 + BUF;            // attn1 fp32
  ushort* u = (ushort*)(at1_32 + BUF);
  ushort* bx16 = u;  u += BUF;           // x bf16
  ushort* v16  = u;  u += BUF;           // v bf16
  ushort* o16  = u;  u += BUF;           // sampled o bf16
  ushort* a116 = u;  u += BUF;           // attn1 bf16
  ushort* a216 = u;  u += BUF;           // attn2 bf16
  ushort* Btw  = u;  u += (size_t)7*65536;
  float* bcatA = (float*)u;
  float* bcatB = bcatA + 256;

  dim3 gdwg(PIX/64, 4, 2);    // 1024 blocks
  dim3 ggem(PIX/64, 4);       // 512 blocks

  k_prep<<<2497, 256, 0, stream>>>(x, bx32, bx16,
      a_in_w, a_off_w, a_mk_w, a_out_w, b_in_w, b_off_w, b_mk_w, b_out_w, proj_w, Btw,
      a_off_b, a_mk_b, b_off_b, b_mk_b, bcatA, bcatB);

  // ---- layer a ----
  k_dwg<<<gdwg, 256, 0, stream>>>(bx32, bx16,
      a_dw_w, a_dw_b, a_ln_g, a_ln_b,
      Btw + 0*65536, a_in_b, Btw + 1*65536, bcatA, v16, fm32);
  k_sample<<<PIX/4, 256, 0, stream>>>(v16, fm32, o16);
  k_gemm256<1><<<ggem, 256, 0, stream>>>(o16, Btw + 2*65536, a_out_b, at1_32, a116, nullptr, nullptr);

  // ---- layer b ----
  k_dwg<<<gdwg, 256, 0, stream>>>(at1_32, a116,
      b_dw_w, b_dw_b, b_ln_g, b_ln_b,
      Btw + 3*65536, b_in_b, Btw + 4*65536, bcatB, v16, fm32);
  k_sample<<<PIX/4, 256, 0, stream>>>(v16, fm32, o16);
  k_gemm256<0><<<ggem, 256, 0, stream>>>(o16, Btw + 5*65536, b_out_b, nullptr, a216, nullptr, nullptr);

  // ---- final proj fused with gate ----
  k_gemm256<3><<<ggem, 256, 0, stream>>>(a216, Btw + 6*65536, proj_b, nullptr, nullptr, x, out);
}

// Round 8
// 95.021 us; speedup vs baseline: 1.6958x; 1.6958x over previous
//
#include <hip/hip_runtime.h>
#include <hip/hip_bf16.h>
#include <math.h>

#define HH 64
#define WW 64
#define CH 256
#define NB 2
#define HWSZ (HH*WW)        // 4096
#define PIX (NB*HWSZ)       // 8192

typedef __attribute__((ext_vector_type(8))) short bf16x8;
typedef __attribute__((ext_vector_type(4))) float f32x4;

static __device__ __forceinline__ ushort f2bf(float f){
  union { __hip_bfloat16 h; ushort u; } cv;
  cv.h = __float2bfloat16(f);   // round-to-nearest-even
  return cv.u;
}
static __device__ __forceinline__ float bflo(uint u){ return __uint_as_float(u << 16); }
static __device__ __forceinline__ float bfhi(uint u){ return __uint_as_float(u & 0xffff0000u); }

// ---------------- prep: b<2048 NCHW->NHWC transpose; 2048..2495 weight prep; 2496 bias ----------------
__global__ __launch_bounds__(256) void k_prep(const float* __restrict__ x,
    float* __restrict__ out32, ushort* __restrict__ out16,
    const float* __restrict__ a_in_w, const float* __restrict__ a_off_w,
    const float* __restrict__ a_mk_w, const float* __restrict__ a_out_w,
    const float* __restrict__ b_in_w, const float* __restrict__ b_off_w,
    const float* __restrict__ b_mk_w, const float* __restrict__ b_out_w,
    const float* __restrict__ proj_w, ushort* __restrict__ Bt,
    const float* __restrict__ a_off_b, const float* __restrict__ a_mk_b,
    const float* __restrict__ b_off_b, const float* __restrict__ b_mk_b,
    float* __restrict__ bcatA, float* __restrict__ bcatB){
  __shared__ float t[32][33];
  int b = blockIdx.x;
  int tid = threadIdx.x;
  int tx = tid & 31, ty = tid >> 5;           // 32 x 8
  if (b < 2048) {
    int n = b >> 10, rem = b & 1023;
    int p0 = (rem & 127) * 32, c0 = (rem >> 7) * 32;
    const float* inn = x + (size_t)n * CH * HWSZ;
    float* o32 = out32 + (size_t)n * HWSZ * CH;
    ushort* o16 = out16 + (size_t)n * HWSZ * CH;
    #pragma unroll
    for (int i = 0; i < 4; ++i) {
      int c = c0 + ty + i*8;
      t[ty + i*8][tx] = inn[(size_t)c * HWSZ + p0 + tx];
    }
    __syncthreads();
    #pragma unroll
    for (int i = 0; i < 4; ++i) {
      int p = p0 + ty + i*8;
      float val = t[tx][ty + i*8];
      o32[(size_t)p * CH + c0 + tx] = val;
      o16[(size_t)p * CH + c0 + tx] = f2bf(val);
    }
  } else if (b < 2496) {
    int zz = b - 2048;
    int z = zz >> 6, rem = zz & 63;
    int n0 = (rem & 7) * 32, k0 = (rem >> 3) * 32;
    const float* W = a_in_w; int mode = 0;
    switch(z){
      case 0: W = a_in_w; break;
      case 1: mode = 1; break;
      case 2: W = a_out_w; break;
      case 3: W = b_in_w; break;
      case 4: mode = 2; break;
      case 5: W = b_out_w; break;
      default: W = proj_w; break;
    }
    #pragma unroll
    for (int i = 0; i < 4; ++i) {
      int k = k0 + ty + i*8, nn = n0 + tx;
      float val;
      if (mode == 0) val = W[k*256 + nn];
      else {
        const float* ow = (mode == 1) ? a_off_w : b_off_w;
        const float* mw = (mode == 1) ? a_mk_w  : b_mk_w;
        val = (nn < 144) ? ow[k*144 + nn] : ((nn < 216) ? mw[k*72 + nn - 144] : 0.f);
      }
      t[ty + i*8][tx] = val;
    }
    __syncthreads();
    #pragma unroll
    for (int i = 0; i < 4; ++i) {
      int nn = n0 + ty + i*8, k = k0 + tx;
      Bt[(size_t)z*65536 + nn*256 + k] = f2bf(t[tx][ty + i*8]);
    }
  } else {
    bcatA[tid] = (tid < 144) ? a_off_b[tid] : ((tid < 216) ? a_mk_b[tid-144] : 0.f);
    bcatB[tid] = (tid < 144) ? b_off_b[tid] : ((tid < 216) ? b_mk_b[tid-144] : 0.f);
  }
}

// ---------------- fused depthwise 3x3 + LayerNorm + GELU -> bf16 (wave-per-pixel) ----------------
__global__ __launch_bounds__(256) void k_dwln(const float* __restrict__ xin,
    const float* __restrict__ dw_w, const float* __restrict__ dw_b,
    const float* __restrict__ ln_g, const float* __restrict__ ln_b,
    ushort* __restrict__ f){
  int w_ = threadIdx.x >> 6, l = threadIdx.x & 63;
  int pix = blockIdx.x * 4 + w_;
  int c = l << 2;
  int n  = pix >> 12;
  int hw = pix & 4095;
  int h = hw >> 6, w = hw & 63;
  const float* xb = xin + (size_t)n * HWSZ * CH;
  float4 bv = *reinterpret_cast<const float4*>(&dw_b[c]);
  float s0 = bv.x, s1 = bv.y, s2 = bv.z, s3 = bv.w;
  #pragma unroll
  for (int i = 0; i < 3; ++i) {
    int y = h + i - 1;
    if ((unsigned)y < 64u) {
      #pragma unroll
      for (int j = 0; j < 3; ++j) {
        int x = w + j - 1;
        if ((unsigned)x < 64u) {
          float4 xv = *reinterpret_cast<const float4*>(&xb[((size_t)((y<<6)+x))*CH + c]);
          float4 wv = *reinterpret_cast<const float4*>(&dw_w[(i*3+j)*CH + c]);
          s0 = fmaf(xv.x, wv.x, s0);
          s1 = fmaf(xv.y, wv.y, s1);
          s2 = fmaf(xv.z, wv.z, s2);
          s3 = fmaf(xv.w, wv.w, s3);
        }
      }
    }
  }
  float v1 = s0 + s1 + s2 + s3;
  float v2 = s0*s0 + s1*s1 + s2*s2 + s3*s3;
  #pragma unroll
  for (int off = 32; off >= 1; off >>= 1) {
    v1 += __shfl_xor(v1, off);
    v2 += __shfl_xor(v2, off);
  }
  float mean = v1 * (1.f/256.f);
  float var  = v2 * (1.f/256.f) - mean*mean;
  float inv  = rsqrtf(var + 1e-5f);
  float4 gv = *reinterpret_cast<const float4*>(&ln_g[c]);
  float4 bb = *reinterpret_cast<const float4*>(&ln_b[c]);
  float z0 = (s0 - mean) * inv * gv.x + bb.x;
  float z1 = (s1 - mean) * inv * gv.y + bb.y;
  float z2 = (s2 - mean) * inv * gv.z + bb.z;
  float z3 = (s3 - mean) * inv * gv.w + bb.w;
  float g0 = 0.5f * z0 * (1.f + erff(z0 * 0.70710678118654752f));
  float g1 = 0.5f * z1 * (1.f + erff(z1 * 0.70710678118654752f));
  float g2 = 0.5f * z2 * (1.f + erff(z2 * 0.70710678118654752f));
  float g3 = 0.5f * z3 * (1.f + erff(z3 * 0.70710678118654752f));
  uint2 pk;
  pk.x = (uint)f2bf(g0) | ((uint)f2bf(g1) << 16);
  pk.y = (uint)f2bf(g2) | ((uint)f2bf(g3) << 16);
  *reinterpret_cast<uint2*>(&f[(size_t)pix*CH + c]) = pk;
}

// ================= shared GEMM core (R7, verified) =================
// As: 64 rows x 256 K bf16, swizzled (chunk ck at ck^(row&31)). 4 K-phases, Bs 8KB streamed
// with register prefetch; 4 waves x 16-col strips; register blocking 4x1.
// MODE: 0 = bf16 out; 1 = f32 + bf16 out; 2 = f32 out; 3 = fused gate (NCHW f32 out)
template<int MODE>
static __device__ __forceinline__ void gemm_core(ushort* As, ushort* Bs,
    int rows, int by, const ushort* __restrict__ Bt, const float* __restrict__ bias,
    float* __restrict__ Cf, ushort* __restrict__ Cb,
    const float* __restrict__ xg, float* __restrict__ outg){
  int tid = threadIdx.x;
  int w = tid >> 6, l = tid & 63;
  int lr = l & 15, lk = l >> 4;          // lk 0..3
  int br = tid >> 2, bc2 = (tid & 3) << 1;     // B staging: row 0..63, 2 chunks each
  const ushort* Bg = Bt + (size_t)(by*64 + br) * 256 + ((tid & 3) << 4);
  uint4 pb0 = *reinterpret_cast<const uint4*>(Bg);
  uint4 pb1 = *reinterpret_cast<const uint4*>(Bg + 8);
  f32x4 acc[4] = {};
  #pragma unroll
  for (int ph = 0; ph < 4; ++ph) {
    __syncthreads();
    *reinterpret_cast<uint4*>(&Bs[(br << 6) + (((bc2    ) ^ (br & 7)) << 3)]) = pb0;
    *reinterpret_cast<uint4*>(&Bs[(br << 6) + (((bc2 + 1) ^ (br & 7)) << 3)]) = pb1;
    __syncthreads();
    if (ph < 3) {
      pb0 = *reinterpret_cast<const uint4*>(Bg + (ph+1)*64);
      pb1 = *reinterpret_cast<const uint4*>(Bg + (ph+1)*64 + 8);
    }
    #pragma unroll
    for (int ks = 0; ks < 2; ++ks) {
      int col = w*16 + lr;
      bf16x8 bf = *reinterpret_cast<const bf16x8*>(&Bs[(col << 6) + ((((ks<<2) + lk) ^ (col & 7)) << 3)]);
      #pragma unroll
      for (int mi = 0; mi < 4; ++mi) {
        int row = mi*16 + lr;
        int ck = ((ph<<3) + (ks<<2) + lk) ^ (row & 31);
        bf16x8 af = *reinterpret_cast<const bf16x8*>(&As[(row << 8) + (ck << 3)]);
        acc[mi] = __builtin_amdgcn_mfma_f32_16x16x32_bf16(af, bf, acc[mi], 0, 0, 0);
      }
    }
  }
  int colg = by*64 + w*16 + lr;
  float bval = bias[colg];
  #pragma unroll
  for (int mi = 0; mi < 4; ++mi) {
    int row0 = rows + mi*16 + (lk << 2);
    if (MODE == 3) {
      int n = row0 >> 12, hw = row0 & 4095;
      size_t base = (size_t)n * (CH*HWSZ) + (size_t)colg * HWSZ + hw;
      float4 xv = *reinterpret_cast<const float4*>(&xg[base]);
      float4 ov;
      ov.x = xv.x * (acc[mi][0] + bval);
      ov.y = xv.y * (acc[mi][1] + bval);
      ov.z = xv.z * (acc[mi][2] + bval);
      ov.w = xv.w * (acc[mi][3] + bval);
      *reinterpret_cast<float4*>(&outg[base]) = ov;
    } else {
      #pragma unroll
      for (int j = 0; j < 4; ++j) {
        float val = acc[mi][j] + bval;
        if (MODE != 0) Cf[(size_t)(row0 + j) * 256 + colg] = val;
        if (MODE != 2) Cb[(size_t)(row0 + j) * 256 + colg] = f2bf(val);
      }
    }
  }
}

// stage A-tile (64x256 bf16) from global into swizzled As
static __device__ __forceinline__ void stage_A(ushort* As, const ushort* __restrict__ A, int rows){
  int tid = threadIdx.x;
  int r = tid >> 2, q0 = (tid & 3) << 3;   // 8 chunks per thread
  const ushort* Ag = A + (size_t)(rows + r) * 256 + (q0 << 3);
  #pragma unroll
  for (int i = 0; i < 8; ++i) {
    uint4 v = *reinterpret_cast<const uint4*>(Ag + (i << 3));
    *reinterpret_cast<uint4*>(&As[(r << 8) + (((q0 + i) ^ (r & 31)) << 3)]) = v;
  }
}

// ================= plain GEMM kernel (A from global bf16) =================
template<int MODE>
__global__ __launch_bounds__(256, 4) void k_gemm256(const ushort* __restrict__ A,
    const ushort* __restrict__ Bt, const float* __restrict__ bias,
    float* __restrict__ Cf, ushort* __restrict__ Cb,
    const float* __restrict__ xg, float* __restrict__ outg){
  __shared__ ushort As[64*256];
  __shared__ ushort Bs[64*64];
  int rows = blockIdx.x * 64, by = blockIdx.y;
  stage_A(As, A, rows);
  gemm_core<MODE>(As, Bs, rows, by, Bt, bias, Cf, Cb, xg, outg);
}

// ================= merged v-GEMM (z=0) + fm-GEMM (z=1), both A from global =================
__global__ __launch_bounds__(256, 4) void k_vfm(
    const ushort* __restrict__ Av, const ushort* __restrict__ Btv,
    const float* __restrict__ biasv, ushort* __restrict__ v16,
    const ushort* __restrict__ Af, const ushort* __restrict__ Btf,
    const float* __restrict__ biasf, float* __restrict__ fm32){
  __shared__ ushort As[64*256];
  __shared__ ushort Bs[64*64];
  int rows = blockIdx.x * 64, by = blockIdx.y;
  if (blockIdx.z == 0) {
    stage_A(As, Av, rows);
    gemm_core<0>(As, Bs, rows, by, Btv, biasv, nullptr, v16, nullptr, nullptr);
  } else {
    stage_A(As, Af, rows);
    gemm_core<2>(As, Bs, rows, by, Btf, biasf, fm32, nullptr, nullptr, nullptr);
  }
}

// ---------------- deformable sampling (wave-per-pixel, 4 ch/thread, uint2 gathers) ----------------
__global__ __launch_bounds__(256, 4) void k_sample(const ushort* __restrict__ v,
    const float* __restrict__ fm, ushort* __restrict__ o){
  __shared__ float sfm[4][256];
  int wv = threadIdx.x >> 6, l = threadIdx.x & 63;
  int pix = blockIdx.x * 4 + wv;
  int c = l << 2;
  int g = l >> 3;
  *reinterpret_cast<float4*>(&sfm[wv][c]) = *reinterpret_cast<const float4*>(&fm[(size_t)pix*256 + c]);
  __syncthreads();
  const float* fp = sfm[wv];
  float ml[9];
  float mx = -1e30f;
  #pragma unroll
  for (int k = 0; k < 9; ++k) { ml[k] = fp[144 + g*9 + k]; mx = fmaxf(mx, ml[k]); }
  float ssum = 0.f;
  #pragma unroll
  for (int k = 0; k < 9; ++k) { ml[k] = __expf(ml[k] - mx); ssum += ml[k]; }
  int n = pix >> 12;
  int hw = pix & 4095;
  int h = hw >> 6, w = hw & 63;
  const ushort* vb = v + (size_t)n * HWSZ * CH + c;
  float a0 = 0.f, a1 = 0.f, a2 = 0.f, a3 = 0.f;
  #pragma unroll
  for (int k = 0; k < 9; ++k) {
    int dx = k/3 - 1, dy = k%3 - 1;     // dx-major per meshgrid(indexing='ij')
    float ox = fp[g*18 + k*2];
    float oy = fp[g*18 + k*2 + 1];
    float xu = (float)(w + dx) + ox;
    float yu = (float)(h + dy) + oy;
    float xf = floorf(xu), yf = floorf(yu);
    float tx = xu - xf, ty = yu - yf;
    int x0 = (int)xf, y0 = (int)yf;
    int x1 = x0 + 1, y1 = y0 + 1;
    float m00 = (float)((unsigned)x0 < 64u && (unsigned)y0 < 64u);
    float m10 = (float)((unsigned)x1 < 64u && (unsigned)y0 < 64u);
    float m01 = (float)((unsigned)x0 < 64u && (unsigned)y1 < 64u);
    float m11 = (float)((unsigned)x1 < 64u && (unsigned)y1 < 64u);
    int xc0 = min(max(x0, 0), 63), xc1 = min(max(x1, 0), 63);
    int yc0 = min(max(y0, 0), 63), yc1 = min(max(y1, 0), 63);
    float w0x = 1.f - tx, w0y = 1.f - ty;
    uint2 q00 = *reinterpret_cast<const uint2*>(vb + (((yc0 << 6) + xc0) << 8));
    uint2 q10 = *reinterpret_cast<const uint2*>(vb + (((yc0 << 6) + xc1) << 8));
    uint2 q01 = *reinterpret_cast<const uint2*>(vb + (((yc1 << 6) + xc0) << 8));
    uint2 q11 = *reinterpret_cast<const uint2*>(vb + (((yc1 << 6) + xc1) << 8));
    float w00 = ml[k] * (w0x * w0y * m00);
    float w10 = ml[k] * (tx  * w0y * m10);
    float w01 = ml[k] * (w0x * ty  * m01);
    float w11 = ml[k] * (tx  * ty  * m11);
    a0 = fmaf(bflo(q00.x), w00, a0); a1 = fmaf(bfhi(q00.x), w00, a1);
    a2 = fmaf(bflo(q00.y), w00, a2); a3 = fmaf(bfhi(q00.y), w00, a3);
    a0 = fmaf(bflo(q10.x), w10, a0); a1 = fmaf(bfhi(q10.x), w10, a1);
    a2 = fmaf(bflo(q10.y), w10, a2); a3 = fmaf(bfhi(q10.y), w10, a3);
    a0 = fmaf(bflo(q01.x), w01, a0); a1 = fmaf(bfhi(q01.x), w01, a1);
    a2 = fmaf(bflo(q01.y), w01, a2); a3 = fmaf(bfhi(q01.y), w01, a3);
    a0 = fmaf(bflo(q11.x), w11, a0); a1 = fmaf(bfhi(q11.x), w11, a1);
    a2 = fmaf(bflo(q11.y), w11, a2); a3 = fmaf(bfhi(q11.y), w11, a3);
  }
  float inv = 1.f / ssum;
  uint2 pk;
  pk.x = (uint)f2bf(a0 * inv) | ((uint)f2bf(a1 * inv) << 16);
  pk.y = (uint)f2bf(a2 * inv) | ((uint)f2bf(a3 * inv) << 16);
  *reinterpret_cast<uint2*>(&o[(size_t)pix*256 + c]) = pk;
}

extern "C" void kernel_launch(void* const* d_in, const int* in_sizes, int n_in,
                              void* d_out, int out_size, void* d_ws, size_t ws_size,
                              hipStream_t stream) {
  const float* x      = (const float*)d_in[0];
  const float* a_dw_w = (const float*)d_in[1];
  const float* a_dw_b = (const float*)d_in[2];
  const float* a_ln_g = (const float*)d_in[3];
  const float* a_ln_b = (const float*)d_in[4];
  const float* a_in_w = (const float*)d_in[5];
  const float* a_in_b = (const float*)d_in[6];
  const float* a_off_w= (const float*)d_in[7];
  const float* a_off_b= (const float*)d_in[8];
  const float* a_mk_w = (const float*)d_in[9];
  const float* a_mk_b = (const float*)d_in[10];
  const float* a_out_w= (const float*)d_in[11];
  const float* a_out_b= (const float*)d_in[12];
  const float* b_dw_w = (const float*)d_in[13];
  const float* b_dw_b = (const float*)d_in[14];
  const float* b_ln_g = (const float*)d_in[15];
  const float* b_ln_b = (const float*)d_in[16];
  const float* b_in_w = (const float*)d_in[17];
  const float* b_in_b = (const float*)d_in[18];
  const float* b_off_w= (const float*)d_in[19];
  const float* b_off_b= (const float*)d_in[20];
  const float* b_mk_w = (const float*)d_in[21];
  const float* b_mk_b = (const float*)d_in[22];
  const float* b_out_w= (const float*)d_in[23];
  const float* b_out_b= (const float*)d_in[24];
  const float* proj_w = (const float*)d_in[25];
  const float* proj_b = (const float*)d_in[26];
  float* out = (float*)d_out;

  const size_t BUF = (size_t)PIX * CH;   // 2,097,152 elements
  float* bx32   = (float*)d_ws;          // x NHWC fp32
  float* fm32   = bx32 + BUF;            // offsets+mask logits fp32
  float* at1_32 = fm32 + BUF;            // attn1 fp32
  ushort* u = (ushort*)(at1_32 + BUF);
  ushort* bx16 = u;  u += BUF;           // x bf16
  ushort* f16  = u;  u += BUF;           // dwln output bf16
  ushort* v16  = u;  u += BUF;           // v bf16
  ushort* o16  = u;  u += BUF;           // sampled o bf16
  ushort* a116 = u;  u += BUF;           // attn1 bf16
  ushort* a216 = u;  u += BUF;           // attn2 bf16
  ushort* Btw  = u;  u += (size_t)7*65536;
  float* bcatA = (float*)u;
  float* bcatB = bcatA + 256;

  dim3 gvfm(PIX/64, 4, 2);    // 1024 blocks
  dim3 ggem(PIX/64, 4);       // 512 blocks

  k_prep<<<2497, 256, 0, stream>>>(x, bx32, bx16,
      a_in_w, a_off_w, a_mk_w, a_out_w, b_in_w, b_off_w, b_mk_w, b_out_w, proj_w, Btw,
      a_off_b, a_mk_b, b_off_b, b_mk_b, bcatA, bcatB);

  // ---- layer a ----
  k_dwln<<<PIX/4, 256, 0, stream>>>(bx32, a_dw_w, a_dw_b, a_ln_g, a_ln_b, f16);
  k_vfm<<<gvfm, 256, 0, stream>>>(bx16, Btw + 0*65536, a_in_b, v16,
                                  f16, Btw + 1*65536, bcatA, fm32);
  k_sample<<<PIX/4, 256, 0, stream>>>(v16, fm32, o16);
  k_gemm256<1><<<ggem, 256, 0, stream>>>(o16, Btw + 2*65536, a_out_b, at1_32, a116, nullptr, nullptr);

  // ---- layer b ----
  k_dwln<<<PIX/4, 256, 0, stream>>>(at1_32, b_dw_w, b_dw_b, b_ln_g, b_ln_b, f16);
  k_vfm<<<gvfm, 256, 0, stream>>>(a116, Btw + 3*65536, b_in_b, v16,
                                  f16, Btw + 4*65536, bcatB, fm32);
  k_sample<<<PIX/4, 256, 0, stream>>>(v16, fm32, o16);
  k_gemm256<0><<<ggem, 256, 0, stream>>>(o16, Btw + 5*65536, b_out_b, nullptr, a216, nullptr, nullptr);

  // ---- final proj fused with gate ----
  k_gemm256<3><<<ggem, 256, 0, stream>>>(a216, Btw + 6*65536, proj_b, nullptr, nullptr, x, out);
}